// Round 1
// baseline (1865.899 us; speedup 1.0000x reference)
//
#include <hip/hip_runtime.h>
#include <cstddef>

#define MIN_VALUE_F (-3.402823466e38f)

// B=4, C=64, T=256, D=256, H=4, DK=64, OUT=256, M = B*C*T = 65536

__device__ __forceinline__ float bf2f(unsigned int u) {
    union { unsigned int i; float f; } v; v.i = u << 16; return v.f;
}
__device__ __forceinline__ unsigned short f2bf(float f) {
    union { float f; unsigned int i; } v; v.f = f;
    return (unsigned short)((v.i + 0x7fffu + ((v.i >> 16) & 1u)) >> 16);
}
__device__ __forceinline__ void unpack8(const uint4 u, float* dst) {
    dst[0] = bf2f(u.x & 0xffffu); dst[1] = bf2f(u.x >> 16);
    dst[2] = bf2f(u.y & 0xffffu); dst[3] = bf2f(u.y >> 16);
    dst[4] = bf2f(u.z & 0xffffu); dst[5] = bf2f(u.z >> 16);
    dst[6] = bf2f(u.w & 0xffffu); dst[7] = bf2f(u.w >> 16);
}

// ---------------- Stage 1: complex QKV projection ----------------
// out_r = xr@wr - xi@wi + (br - bi); out_i = xi@wr + xr@wi + (br + bi)
// x: (M=65536, 256) f32 row-major (== (B,C,T,D)); w: (256,256); out: bf16 in
// head-split layout (B,H,T,C,DK), tile n0 = 64*h so h == blockIdx.y.
__global__ __launch_bounds__(256)
void proj_kernel(const float* __restrict__ xr, const float* __restrict__ xi,
                 const float* __restrict__ wr, const float* __restrict__ wi,
                 const float* __restrict__ br, const float* __restrict__ bi,
                 unsigned short* __restrict__ outr, unsigned short* __restrict__ outi)
{
    __shared__ float Ar[64][36], Ai[64][36];   // x tile 64 rows x 32 k (pad->36: 16B-aligned rows, spread banks)
    __shared__ float Wr[32][68], Wi[32][68];   // w tile 32 k x 64 n
    const int m0 = blockIdx.x * 64;
    const int n0 = blockIdx.y * 64;
    const int tid = threadIdx.x;
    const int tx = tid & 15, ty = tid >> 4;
    float accR[4][4] = {}, accI[4][4] = {};

    for (int k0 = 0; k0 < 256; k0 += 32) {
        {   // A tiles (f32, float4 loads)
            const int r = tid >> 3;
            const int cg = (tid & 7) << 2;
            #pragma unroll
            for (int rr = 0; rr < 64; rr += 32) {
                const float4 a = *(const float4*)(xr + (size_t)(m0 + r + rr) * 256 + k0 + cg);
                const float4 b = *(const float4*)(xi + (size_t)(m0 + r + rr) * 256 + k0 + cg);
                *(float4*)&Ar[r + rr][cg] = a;
                *(float4*)&Ai[r + rr][cg] = b;
            }
        }
        {   // W tiles
            const int r = tid >> 4;
            const int cg = (tid & 15) << 2;
            #pragma unroll
            for (int rr = 0; rr < 32; rr += 16) {
                *(float4*)&Wr[r + rr][cg] = *(const float4*)(wr + (size_t)(k0 + r + rr) * 256 + n0 + cg);
                *(float4*)&Wi[r + rr][cg] = *(const float4*)(wi + (size_t)(k0 + r + rr) * 256 + n0 + cg);
            }
        }
        __syncthreads();
        #pragma unroll
        for (int kq = 0; kq < 32; kq += 4) {
            float4 arv[4], aiv[4];
            #pragma unroll
            for (int i = 0; i < 4; ++i) {
                arv[i] = *(const float4*)&Ar[ty + 16 * i][kq];
                aiv[i] = *(const float4*)&Ai[ty + 16 * i][kq];
            }
            #pragma unroll
            for (int kk = 0; kk < 4; ++kk) {
                float wrv[4], wiv[4];
                #pragma unroll
                for (int j = 0; j < 4; ++j) {
                    wrv[j] = Wr[kq + kk][tx + 16 * j];
                    wiv[j] = Wi[kq + kk][tx + 16 * j];
                }
                #pragma unroll
                for (int i = 0; i < 4; ++i) {
                    const float ar = ((const float*)&arv[i])[kk];
                    const float ai = ((const float*)&aiv[i])[kk];
                    #pragma unroll
                    for (int j = 0; j < 4; ++j) {
                        accR[i][j] = fmaf(ar, wrv[j], accR[i][j]);
                        accR[i][j] = fmaf(-ai, wiv[j], accR[i][j]);
                        accI[i][j] = fmaf(ai, wrv[j], accI[i][j]);
                        accI[i][j] = fmaf(ar, wiv[j], accI[i][j]);
                    }
                }
            }
        }
        __syncthreads();
    }
    // epilogue: bias + bf16 store scattered to (B,H,T,C,DK)
    const int h = blockIdx.y;
    #pragma unroll
    for (int i = 0; i < 4; ++i) {
        const int m = m0 + ty + 16 * i;
        const int t = m & 255;
        const int bc = m >> 8;
        const int c = bc & 63;
        const int b = bc >> 6;
        const size_t obase = (((size_t)(b * 4 + h) * 256 + t) * 64 + c) * 64;
        #pragma unroll
        for (int j = 0; j < 4; ++j) {
            const int n = n0 + tx + 16 * j;
            const float vbr = br[n], vbi = bi[n];
            outr[obase + tx + 16 * j] = f2bf(accR[i][j] + vbr - vbi);
            outi[obase + tx + 16 * j] = f2bf(accI[i][j] + vbr + vbi);
        }
    }
}

// ---------------- Stage 2: fused complex attention per (b,h,t) ----------------
__global__ __launch_bounds__(256)
void attn_kernel(const unsigned short* __restrict__ Qr, const unsigned short* __restrict__ Qi,
                 const unsigned short* __restrict__ Kr, const unsigned short* __restrict__ Ki,
                 const unsigned short* __restrict__ Vr, const unsigned short* __restrict__ Vi,
                 const int* __restrict__ mask,
                 unsigned short* __restrict__ Xr, unsigned short* __restrict__ Xi)
{
    __shared__ float tAr[64][68], tAi[64][68];   // Q, then attention weights a
    __shared__ float tBr[64][68], tBi[64][68];   // K, then V
    const int bht = blockIdx.x;          // ((b*H + h)*T + t)
    const int b = bht >> 10;
    const int h = (bht >> 8) & 3;
    const int t = bht & 255;
    const size_t base = (size_t)bht * 4096;
    const int tid = threadIdx.x;

    {   // load Q,K (64x64 bf16 each) -> LDS f32
        const int r = tid >> 2;
        const int cg = (tid & 3) << 4;
        const size_t off = base + (size_t)r * 64 + cg;
        uint4 a0 = ((const uint4*)(Qr + off))[0], a1 = ((const uint4*)(Qr + off))[1];
        uint4 b0 = ((const uint4*)(Qi + off))[0], b1 = ((const uint4*)(Qi + off))[1];
        uint4 c0v = ((const uint4*)(Kr + off))[0], c1 = ((const uint4*)(Kr + off))[1];
        uint4 d0v = ((const uint4*)(Ki + off))[0], d1 = ((const uint4*)(Ki + off))[1];
        unpack8(a0, &tAr[r][cg]); unpack8(a1, &tAr[r][cg + 8]);
        unpack8(b0, &tAi[r][cg]); unpack8(b1, &tAi[r][cg + 8]);
        unpack8(c0v, &tBr[r][cg]); unpack8(c1, &tBr[r][cg + 8]);
        unpack8(d0v, &tBi[r][cg]); unpack8(d1, &tBi[r][cg + 8]);
    }
    __syncthreads();

    // ---- scores: s[c][e] = sum_d conj(q[c])*k[e], thread: rows {c0,c0+32}, e = eg + 8*ee
    const int c0 = tid >> 3;
    const int eg = tid & 7;
    float sR[2][8] = {}, sI[2][8] = {};
    for (int d0 = 0; d0 < 64; d0 += 8) {
        float q0r[8], q0i[8], q1r[8], q1i[8];
        *(float4*)&q0r[0] = *(const float4*)&tAr[c0][d0];
        *(float4*)&q0r[4] = *(const float4*)&tAr[c0][d0 + 4];
        *(float4*)&q0i[0] = *(const float4*)&tAi[c0][d0];
        *(float4*)&q0i[4] = *(const float4*)&tAi[c0][d0 + 4];
        *(float4*)&q1r[0] = *(const float4*)&tAr[c0 + 32][d0];
        *(float4*)&q1r[4] = *(const float4*)&tAr[c0 + 32][d0 + 4];
        *(float4*)&q1i[0] = *(const float4*)&tAi[c0 + 32][d0];
        *(float4*)&q1i[4] = *(const float4*)&tAi[c0 + 32][d0 + 4];
        #pragma unroll
        for (int ee = 0; ee < 8; ++ee) {
            const int e = eg + 8 * ee;
            float kvr[8], kvi[8];
            *(float4*)&kvr[0] = *(const float4*)&tBr[e][d0];
            *(float4*)&kvr[4] = *(const float4*)&tBr[e][d0 + 4];
            *(float4*)&kvi[0] = *(const float4*)&tBi[e][d0];
            *(float4*)&kvi[4] = *(const float4*)&tBi[e][d0 + 4];
            #pragma unroll
            for (int d = 0; d < 8; ++d) {
                sR[0][ee] = fmaf(q0r[d], kvr[d], sR[0][ee]);
                sR[0][ee] = fmaf(q0i[d], kvi[d], sR[0][ee]);
                sI[0][ee] = fmaf(q0r[d], kvi[d], sI[0][ee]);
                sI[0][ee] = fmaf(-q0i[d], kvr[d], sI[0][ee]);
                sR[1][ee] = fmaf(q1r[d], kvr[d], sR[1][ee]);
                sR[1][ee] = fmaf(q1i[d], kvi[d], sR[1][ee]);
                sI[1][ee] = fmaf(q1r[d], kvi[d], sI[1][ee]);
                sI[1][ee] = fmaf(-q1i[d], kvr[d], sI[1][ee]);
            }
        }
    }
    __syncthreads();   // all Q/K LDS reads complete

    {   // load V into tB (overwrite K)
        const int r = tid >> 2;
        const int cg = (tid & 3) << 4;
        const size_t off = base + (size_t)r * 64 + cg;
        uint4 v0 = ((const uint4*)(Vr + off))[0], v1 = ((const uint4*)(Vr + off))[1];
        uint4 w0 = ((const uint4*)(Vi + off))[0], w1 = ((const uint4*)(Vi + off))[1];
        unpack8(v0, &tBr[r][cg]); unpack8(v1, &tBr[r][cg + 8]);
        unpack8(w0, &tBi[r][cg]); unpack8(w1, &tBi[r][cg + 8]);
    }

    // ---- amplitude softmax (registers + 8-lane shuffle), write a into tA
    {
        const float scale = 0.125f;    // 1/sqrt(64)
        float amp[2][8], ex[2][8];
        int mk[8];
        #pragma unroll
        for (int ee = 0; ee < 8; ++ee) mk[ee] = mask[b * 64 + eg + 8 * ee];
        float mx[2] = {-INFINITY, -INFINITY};
        #pragma unroll
        for (int j = 0; j < 2; ++j)
            #pragma unroll
            for (int ee = 0; ee < 8; ++ee) {
                const float srv = sR[j][ee] * scale, siv = sI[j][ee] * scale;
                sR[j][ee] = srv; sI[j][ee] = siv;
                float a = sqrtf(fmaf(srv, srv, siv * siv));
                if (mk[ee] == 0) a = MIN_VALUE_F;
                amp[j][ee] = a;
                mx[j] = fmaxf(mx[j], a);
            }
        #pragma unroll
        for (int off = 1; off < 8; off <<= 1) {
            mx[0] = fmaxf(mx[0], __shfl_xor(mx[0], off, 64));
            mx[1] = fmaxf(mx[1], __shfl_xor(mx[1], off, 64));
        }
        float sm[2] = {0.f, 0.f};
        #pragma unroll
        for (int j = 0; j < 2; ++j)
            #pragma unroll
            for (int ee = 0; ee < 8; ++ee) {
                const float e_ = expf(amp[j][ee] - mx[j]);
                ex[j][ee] = e_; sm[j] += e_;
            }
        #pragma unroll
        for (int off = 1; off < 8; off <<= 1) {
            sm[0] += __shfl_xor(sm[0], off, 64);
            sm[1] += __shfl_xor(sm[1], off, 64);
        }
        #pragma unroll
        for (int j = 0; j < 2; ++j) {
            const int c = c0 + 32 * j;
            #pragma unroll
            for (int ee = 0; ee < 8; ++ee) {
                const int e = eg + 8 * ee;
                const float w = ex[j][ee] / (sm[j] * amp[j][ee]);
                tAr[c][e] = (mk[ee] == 0) ? 0.f : w * sR[j][ee];
                tAi[c][e] = (mk[ee] == 0) ? 0.f : w * sI[j][ee];
            }
        }
    }
    __syncthreads();

    // ---- x[c][d] = sum_e a[c][e] * v[e][d] (complex); thread: rows {c0,c0+32}, d = dg..dg+7
    const int dg = (tid & 7) << 3;
    float xR[2][8] = {}, xI[2][8] = {};
    for (int e0 = 0; e0 < 64; e0 += 8) {
        float a0r[8], a0i[8], a1r[8], a1i[8];
        *(float4*)&a0r[0] = *(const float4*)&tAr[c0][e0];
        *(float4*)&a0r[4] = *(const float4*)&tAr[c0][e0 + 4];
        *(float4*)&a0i[0] = *(const float4*)&tAi[c0][e0];
        *(float4*)&a0i[4] = *(const float4*)&tAi[c0][e0 + 4];
        *(float4*)&a1r[0] = *(const float4*)&tAr[c0 + 32][e0];
        *(float4*)&a1r[4] = *(const float4*)&tAr[c0 + 32][e0 + 4];
        *(float4*)&a1i[0] = *(const float4*)&tAi[c0 + 32][e0];
        *(float4*)&a1i[4] = *(const float4*)&tAi[c0 + 32][e0 + 4];
        #pragma unroll
        for (int ee = 0; ee < 8; ++ee) {
            const int e = e0 + ee;
            float vvr[8], vvi[8];
            *(float4*)&vvr[0] = *(const float4*)&tBr[e][dg];
            *(float4*)&vvr[4] = *(const float4*)&tBr[e][dg + 4];
            *(float4*)&vvi[0] = *(const float4*)&tBi[e][dg];
            *(float4*)&vvi[4] = *(const float4*)&tBi[e][dg + 4];
            #pragma unroll
            for (int d = 0; d < 8; ++d) {
                xR[0][d] = fmaf(a0r[ee], vvr[d], xR[0][d]);
                xR[0][d] = fmaf(-a0i[ee], vvi[d], xR[0][d]);
                xI[0][d] = fmaf(a0i[ee], vvr[d], xI[0][d]);
                xI[0][d] = fmaf(a0r[ee], vvi[d], xI[0][d]);
                xR[1][d] = fmaf(a1r[ee], vvr[d], xR[1][d]);
                xR[1][d] = fmaf(-a1i[ee], vvi[d], xR[1][d]);
                xI[1][d] = fmaf(a1i[ee], vvr[d], xI[1][d]);
                xI[1][d] = fmaf(a1r[ee], vvi[d], xI[1][d]);
            }
        }
    }
    // store x (bf16) to (B,C,T,D) layout: feature = h*64 + d
    #pragma unroll
    for (int j = 0; j < 2; ++j) {
        const int c = c0 + 32 * j;
        const size_t xo = (((size_t)(b * 64 + c) * 256) + t) * 256 + h * 64 + dg;
        uint4 ur, ui;
        ur.x = (unsigned)f2bf(xR[j][0]) | ((unsigned)f2bf(xR[j][1]) << 16);
        ur.y = (unsigned)f2bf(xR[j][2]) | ((unsigned)f2bf(xR[j][3]) << 16);
        ur.z = (unsigned)f2bf(xR[j][4]) | ((unsigned)f2bf(xR[j][5]) << 16);
        ur.w = (unsigned)f2bf(xR[j][6]) | ((unsigned)f2bf(xR[j][7]) << 16);
        ui.x = (unsigned)f2bf(xI[j][0]) | ((unsigned)f2bf(xI[j][1]) << 16);
        ui.y = (unsigned)f2bf(xI[j][2]) | ((unsigned)f2bf(xI[j][3]) << 16);
        ui.z = (unsigned)f2bf(xI[j][4]) | ((unsigned)f2bf(xI[j][5]) << 16);
        ui.w = (unsigned)f2bf(xI[j][6]) | ((unsigned)f2bf(xI[j][7]) << 16);
        *(uint4*)(Xr + xo) = ur;
        *(uint4*)(Xi + xo) = ui;
    }
}

// ---------------- Stage 3: complex output projection ----------------
__global__ __launch_bounds__(256)
void oproj_kernel(const unsigned short* __restrict__ xr, const unsigned short* __restrict__ xi,
                  const float* __restrict__ wr, const float* __restrict__ wi,
                  const float* __restrict__ br, const float* __restrict__ bi,
                  float* __restrict__ outr, float* __restrict__ outi)
{
    __shared__ float Ar[64][36], Ai[64][36];
    __shared__ float Wr[32][68], Wi[32][68];
    const int m0 = blockIdx.x * 64;
    const int n0 = blockIdx.y * 64;
    const int tid = threadIdx.x;
    const int tx = tid & 15, ty = tid >> 4;
    float accR[4][4] = {}, accI[4][4] = {};

    for (int k0 = 0; k0 < 256; k0 += 32) {
        {   // A tiles (bf16 -> f32)
            const int r = tid >> 3;
            const int cg = (tid & 7) << 2;
            #pragma unroll
            for (int rr = 0; rr < 64; rr += 32) {
                const ushort4 a = *(const ushort4*)(xr + (size_t)(m0 + r + rr) * 256 + k0 + cg);
                const ushort4 c = *(const ushort4*)(xi + (size_t)(m0 + r + rr) * 256 + k0 + cg);
                Ar[r + rr][cg + 0] = bf2f(a.x); Ar[r + rr][cg + 1] = bf2f(a.y);
                Ar[r + rr][cg + 2] = bf2f(a.z); Ar[r + rr][cg + 3] = bf2f(a.w);
                Ai[r + rr][cg + 0] = bf2f(c.x); Ai[r + rr][cg + 1] = bf2f(c.y);
                Ai[r + rr][cg + 2] = bf2f(c.z); Ai[r + rr][cg + 3] = bf2f(c.w);
            }
        }
        {   // W tiles
            const int r = tid >> 4;
            const int cg = (tid & 15) << 2;
            #pragma unroll
            for (int rr = 0; rr < 32; rr += 16) {
                *(float4*)&Wr[r + rr][cg] = *(const float4*)(wr + (size_t)(k0 + r + rr) * 256 + n0 + cg);
                *(float4*)&Wi[r + rr][cg] = *(const float4*)(wi + (size_t)(k0 + r + rr) * 256 + n0 + cg);
            }
        }
        __syncthreads();
        #pragma unroll
        for (int kq = 0; kq < 32; kq += 4) {
            float4 arv[4], aiv[4];
            #pragma unroll
            for (int i = 0; i < 4; ++i) {
                arv[i] = *(const float4*)&Ar[ty + 16 * i][kq];
                aiv[i] = *(const float4*)&Ai[ty + 16 * i][kq];
            }
            #pragma unroll
            for (int kk = 0; kk < 4; ++kk) {
                float wrv[4], wiv[4];
                #pragma unroll
                for (int j = 0; j < 4; ++j) {
                    wrv[j] = Wr[kq + kk][tx + 16 * j];
                    wiv[j] = Wi[kq + kk][tx + 16 * j];
                }
                #pragma unroll
                for (int i = 0; i < 4; ++i) {
                    const float ar = ((const float*)&arv[i])[kk];
                    const float ai = ((const float*)&aiv[i])[kk];
                    #pragma unroll
                    for (int j = 0; j < 4; ++j) {
                        accR[i][j] = fmaf(ar, wrv[j], accR[i][j]);
                        accR[i][j] = fmaf(-ai, wiv[j], accR[i][j]);
                        accI[i][j] = fmaf(ai, wrv[j], accI[i][j]);
                        accI[i][j] = fmaf(ar, wiv[j], accI[i][j]);
                    }
                }
            }
        }
        __syncthreads();
    }
    #pragma unroll
    for (int i = 0; i < 4; ++i) {
        const size_t m = m0 + ty + 16 * i;
        #pragma unroll
        for (int j = 0; j < 4; ++j) {
            const int n = n0 + tx + 16 * j;
            const float vbr = br[n], vbi = bi[n];
            outr[m * 256 + n] = accR[i][j] + vbr - vbi;
            outi[m * 256 + n] = accI[i][j] + vbr + vbi;
        }
    }
}

extern "C" void kernel_launch(void* const* d_in, const int* in_sizes, int n_in,
                              void* d_out, int out_size, void* d_ws, size_t ws_size,
                              hipStream_t stream)
{
    const float* q_r = (const float*)d_in[0];
    const float* q_i = (const float*)d_in[1];
    const float* k_r = (const float*)d_in[2];
    const float* k_i = (const float*)d_in[3];
    const float* v_r = (const float*)d_in[4];
    const float* v_i = (const float*)d_in[5];
    const int* mask = (const int*)d_in[6];
    const float* wq_r = (const float*)d_in[7];
    const float* wq_i = (const float*)d_in[8];
    const float* bq_r = (const float*)d_in[9];
    const float* bq_i = (const float*)d_in[10];
    const float* wk_r = (const float*)d_in[11];
    const float* wk_i = (const float*)d_in[12];
    const float* bk_r = (const float*)d_in[13];
    const float* bk_i = (const float*)d_in[14];
    const float* wv_r = (const float*)d_in[15];
    const float* wv_i = (const float*)d_in[16];
    const float* bv_r = (const float*)d_in[17];
    const float* bv_i = (const float*)d_in[18];
    const float* wo_r = (const float*)d_in[19];
    const float* wo_i = (const float*)d_in[20];
    const float* bo_r = (const float*)d_in[21];
    const float* bo_i = (const float*)d_in[22];

    const size_t TS = 16777216;   // elements per intermediate tensor
    unsigned short* ws = (unsigned short*)d_ws;
    unsigned short* Qr = ws;            unsigned short* Qi = ws + TS;
    unsigned short* Kr = ws + 2 * TS;   unsigned short* Ki = ws + 3 * TS;
    unsigned short* Vr = ws + 4 * TS;   unsigned short* Vi = ws + 5 * TS;
    unsigned short* Xr = ws + 6 * TS;   unsigned short* Xi = ws + 7 * TS;
    // total ws use: 8 * 32 MiB = 256 MiB

    dim3 blk(256);
    dim3 gP(1024, 4);
    proj_kernel<<<gP, blk, 0, stream>>>(q_r, q_i, wq_r, wq_i, bq_r, bq_i, Qr, Qi);
    proj_kernel<<<gP, blk, 0, stream>>>(k_r, k_i, wk_r, wk_i, bk_r, bk_i, Kr, Ki);
    proj_kernel<<<gP, blk, 0, stream>>>(v_r, v_i, wv_r, wv_i, bv_r, bv_i, Vr, Vi);
    attn_kernel<<<dim3(4096), blk, 0, stream>>>(Qr, Qi, Kr, Ki, Vr, Vi, mask, Xr, Xi);
    oproj_kernel<<<gP, blk, 0, stream>>>(Xr, Xi, wo_r, wo_i, bo_r, bo_i,
                                         (float*)d_out, (float*)d_out + TS);
}

// Round 2
// 561.619 us; speedup vs baseline: 3.3224x; 3.3224x over previous
//
#include <hip/hip_runtime.h>
#include <hip/hip_bf16.h>
#include <cstddef>

#define MIN_VALUE_F (-3.402823466e38f)

// B=4, C=64, T=256, D=256, H=4, DK=64, OUT=256, M = B*C*T = 65536

typedef __attribute__((ext_vector_type(8))) __bf16 bfrag;    // MFMA A/B operand (4 VGPR)
typedef __attribute__((ext_vector_type(4))) float f32x4;     // MFMA C/D operand

__device__ __forceinline__ float bf2f(unsigned int u) {
    union { unsigned int i; float f; } v; v.i = u << 16; return v.f;
}
__device__ __forceinline__ unsigned short f2bf(float f) {
    union { float f; unsigned int i; } v; v.f = f;
    return (unsigned short)((v.i + 0x7fffu + ((v.i >> 16) & 1u)) >> 16);
}
__device__ __forceinline__ unsigned int cvt2(float a, float b) {
    // two f32 -> packed 2x bf16 (RNE); compiler fuses to v_cvt_pk_bf16_f32
    __hip_bfloat16 lo = __float2bfloat16(a);
    __hip_bfloat16 hi = __float2bfloat16(b);
    union { __hip_bfloat16 h[2]; unsigned int u; } x;
    x.h[0] = lo; x.h[1] = hi;
    return x.u;
}
__device__ __forceinline__ void unpack8(const uint4 u, float* dst) {
    dst[0] = bf2f(u.x & 0xffffu); dst[1] = bf2f(u.x >> 16);
    dst[2] = bf2f(u.y & 0xffffu); dst[3] = bf2f(u.y >> 16);
    dst[4] = bf2f(u.z & 0xffffu); dst[5] = bf2f(u.z >> 16);
    dst[6] = bf2f(u.w & 0xffffu); dst[7] = bf2f(u.w >> 16);
}
__device__ __forceinline__ bfrag negf(bfrag v) {
    union { bfrag b; unsigned int u[4]; } x; x.b = v;
    #pragma unroll
    for (int i = 0; i < 4; ++i) x.u[i] ^= 0x80008000u;
    return x.b;
}

typedef __attribute__((address_space(3))) void lds_void_t;
typedef const __attribute__((address_space(1))) void gmem_void_t;
__device__ __forceinline__ void glds16(const void* g, void* l) {
    __builtin_amdgcn_global_load_lds((gmem_void_t*)g, (lds_void_t*)l, 16, 0, 0);
}

// ---------------- Weight prepass: f32 (K=256,N=256) -> bf16 pre-swizzled LDS images ----
// Per matrix: [nb(2)][s(4)] images of 128n x 64k bf16, ushort index (n*64+k)^((n&7)<<3).
__global__ __launch_bounds__(256)
void wprep_kernel(const float* __restrict__ w0, const float* __restrict__ w1,
                  const float* __restrict__ w2, const float* __restrict__ w3,
                  const float* __restrict__ w4, const float* __restrict__ w5,
                  unsigned short* __restrict__ dst)
{
    const int my = blockIdx.y;
    const float* wsrc[6] = {w0, w1, w2, w3, w4, w5};
    const float* w = wsrc[my];
    const int cid = blockIdx.x * 256 + threadIdx.x;   // 0..8191 chunks (16B each)
    const int img = cid >> 10;                        // 0..7  (nb*4 + s)
    const int nb = img >> 2, s = img & 3;
    const int u0 = (cid & 1023) << 3;                 // ushort pos in image
    const int n_loc = u0 >> 6;
    const int k_src = (u0 & 63) ^ ((n_loc & 7) << 3); // unswizzle (16B-block preserving)
    const int n = nb * 128 + n_loc;
    const int kbase = s * 64 + k_src;
    unsigned int p[4];
    #pragma unroll
    for (int jj = 0; jj < 4; ++jj) {
        const float a = w[(size_t)(kbase + 2 * jj) * 256 + n];
        const float b = w[(size_t)(kbase + 2 * jj + 1) * 256 + n];
        p[jj] = cvt2(a, b);
    }
    uint4 q; q.x = p[0]; q.y = p[1]; q.z = p[2]; q.w = p[3];
    *(uint4*)&dst[(size_t)my * 65536 + img * 8192 + u0] = q;
}

// ---------------- Stage 1: complex QKV projection via MFMA ----------------
// blockIdx.z selects q/k/v. Tile 128x128, BK=64, 4 waves of 64x64.
__global__ __launch_bounds__(256, 2)
void proj_mfma(const float* __restrict__ xq_r, const float* __restrict__ xq_i,
               const float* __restrict__ xk_r, const float* __restrict__ xk_i,
               const float* __restrict__ xv_r, const float* __restrict__ xv_i,
               const unsigned short* __restrict__ wimg,   // 6 images (qr,qi,kr,ki,vr,vi)
               const float* __restrict__ bq_r, const float* __restrict__ bq_i,
               const float* __restrict__ bk_r, const float* __restrict__ bk_i,
               const float* __restrict__ bv_r, const float* __restrict__ bv_i,
               unsigned short* __restrict__ ws_out)
{
    __shared__ __align__(16) unsigned short As_r[8192], As_i[8192], Ws_r[8192], Ws_i[8192];
    const int pz = blockIdx.z;
    const float *xr, *xi, *br_, *bi_;
    if (pz == 0)      { xr = xq_r; xi = xq_i; br_ = bq_r; bi_ = bq_i; }
    else if (pz == 1) { xr = xk_r; xi = xk_i; br_ = bk_r; bi_ = bk_i; }
    else              { xr = xv_r; xi = xv_i; br_ = bv_r; bi_ = bv_i; }
    const unsigned short* wr_img = wimg + (size_t)pz * 131072;
    const unsigned short* wi_img = wr_img + 65536;
    unsigned short* outr = ws_out + (size_t)pz * 2 * 16777216;
    unsigned short* outi = outr + 16777216;

    const int tid = threadIdx.x;
    const int lane = tid & 63, wv = tid >> 6;
    const int wm = (wv >> 1) * 64, wn = (wv & 1) * 64;
    const int m0 = blockIdx.x * 128;
    const int nb = blockIdx.y;
    const int sm = tid >> 3;              // staging row 0..31
    const int sk = (tid & 7) << 3;        // staging k 0,8..56
    f32x4 accR[4][4] = {}, accI[4][4] = {};

    for (int s = 0; s < 4; ++s) {
        // W: pre-swizzled bf16 image -> LDS, pure linear global_load_lds
        const unsigned short* wrp = wr_img + (nb * 4 + s) * 8192;
        const unsigned short* wip = wi_img + (nb * 4 + s) * 8192;
        #pragma unroll
        for (int cc = 0; cc < 4; ++cc) {
            const int offs = wv * 2048 + cc * 512;
            glds16(wrp + offs + lane * 8, &Ws_r[offs]);
            glds16(wip + offs + lane * 8, &Ws_i[offs]);
        }
        // A: f32 loads -> bf16 -> swizzled ds_write_b128
        #pragma unroll
        for (int it = 0; it < 4; ++it) {
            const int m = it * 32 + sm;
            const float* sr = xr + (size_t)(m0 + m) * 256 + s * 64 + sk;
            const float* si = xi + (size_t)(m0 + m) * 256 + s * 64 + sk;
            const float4 a0 = *(const float4*)sr;
            const float4 a1 = *(const float4*)(sr + 4);
            const float4 b0 = *(const float4*)si;
            const float4 b1 = *(const float4*)(si + 4);
            const int idx = (m * 64 + sk) ^ ((m & 7) << 3);
            uint4 pr, pi;
            pr.x = cvt2(a0.x, a0.y); pr.y = cvt2(a0.z, a0.w);
            pr.z = cvt2(a1.x, a1.y); pr.w = cvt2(a1.z, a1.w);
            pi.x = cvt2(b0.x, b0.y); pi.y = cvt2(b0.z, b0.w);
            pi.z = cvt2(b1.x, b1.y); pi.w = cvt2(b1.z, b1.w);
            *(uint4*)&As_r[idx] = pr;
            *(uint4*)&As_i[idx] = pi;
        }
        __syncthreads();
        #pragma unroll
        for (int ks = 0; ks < 2; ++ks) {
            const int kb = ks * 32 + ((lane >> 4) << 3);
            bfrag ar[4], ai[4], nai[4];
            #pragma unroll
            for (int mf = 0; mf < 4; ++mf) {
                const int m = wm + mf * 16 + (lane & 15);
                const int idx = (m * 64 + kb) ^ ((m & 7) << 3);
                ar[mf] = *(const bfrag*)&As_r[idx];
                ai[mf] = *(const bfrag*)&As_i[idx];
                nai[mf] = negf(ai[mf]);
            }
            #pragma unroll
            for (int nf = 0; nf < 4; ++nf) {
                const int n = wn + nf * 16 + (lane & 15);
                const int idx = (n * 64 + kb) ^ ((n & 7) << 3);
                const bfrag brf = *(const bfrag*)&Ws_r[idx];
                const bfrag bif = *(const bfrag*)&Ws_i[idx];
                #pragma unroll
                for (int mf = 0; mf < 4; ++mf) {
                    accR[mf][nf] = __builtin_amdgcn_mfma_f32_16x16x32_bf16(ar[mf], brf, accR[mf][nf], 0, 0, 0);
                    accR[mf][nf] = __builtin_amdgcn_mfma_f32_16x16x32_bf16(nai[mf], bif, accR[mf][nf], 0, 0, 0);
                    accI[mf][nf] = __builtin_amdgcn_mfma_f32_16x16x32_bf16(ai[mf], brf, accI[mf][nf], 0, 0, 0);
                    accI[mf][nf] = __builtin_amdgcn_mfma_f32_16x16x32_bf16(ar[mf], bif, accI[mf][nf], 0, 0, 0);
                }
            }
        }
        __syncthreads();
    }
    // epilogue: bias + bf16 scatter to (B,H,T,C,DK). Block covers one (b,c), t-range 128.
    const int bc = m0 >> 8, b = bc >> 6, c = bc & 63, t0 = m0 & 255;
    const int colL = lane & 15, rowL = (lane >> 4) << 2;
    #pragma unroll
    for (int nf = 0; nf < 4; ++nf) {
        const int n_glob = nb * 128 + wn + nf * 16 + colL;
        const int h = n_glob >> 6, dk = n_glob & 63;
        const float vbr = br_[n_glob], vbi = bi_[n_glob];
        const float addR = vbr - vbi, addI = vbr + vbi;
        const size_t baseh = (((size_t)(b * 4 + h) * 256) * 64 + c) * 64 + dk;   // t = 0
        #pragma unroll
        for (int mf = 0; mf < 4; ++mf) {
            const int tb = t0 + wm + mf * 16 + rowL;
            #pragma unroll
            for (int r = 0; r < 4; ++r) {
                const size_t o = baseh + (size_t)(tb + r) * 4096;
                outr[o] = f2bf(accR[mf][nf][r] + addR);
                outi[o] = f2bf(accI[mf][nf][r] + addI);
            }
        }
    }
}

// ---------------- Stage 2: fused complex attention per (b,h,t) (unchanged) ----------------
__global__ __launch_bounds__(256)
void attn_kernel(const unsigned short* __restrict__ Qr, const unsigned short* __restrict__ Qi,
                 const unsigned short* __restrict__ Kr, const unsigned short* __restrict__ Ki,
                 const unsigned short* __restrict__ Vr, const unsigned short* __restrict__ Vi,
                 const int* __restrict__ mask,
                 unsigned short* __restrict__ Xr, unsigned short* __restrict__ Xi)
{
    __shared__ float tAr[64][68], tAi[64][68];
    __shared__ float tBr[64][68], tBi[64][68];
    const int bht = blockIdx.x;
    const int b = bht >> 10;
    const int h = (bht >> 8) & 3;
    const int t = bht & 255;
    const size_t base = (size_t)bht * 4096;
    const int tid = threadIdx.x;

    {
        const int r = tid >> 2;
        const int cg = (tid & 3) << 4;
        const size_t off = base + (size_t)r * 64 + cg;
        uint4 a0 = ((const uint4*)(Qr + off))[0], a1 = ((const uint4*)(Qr + off))[1];
        uint4 b0 = ((const uint4*)(Qi + off))[0], b1 = ((const uint4*)(Qi + off))[1];
        uint4 c0v = ((const uint4*)(Kr + off))[0], c1 = ((const uint4*)(Kr + off))[1];
        uint4 d0v = ((const uint4*)(Ki + off))[0], d1 = ((const uint4*)(Ki + off))[1];
        unpack8(a0, &tAr[r][cg]); unpack8(a1, &tAr[r][cg + 8]);
        unpack8(b0, &tAi[r][cg]); unpack8(b1, &tAi[r][cg + 8]);
        unpack8(c0v, &tBr[r][cg]); unpack8(c1, &tBr[r][cg + 8]);
        unpack8(d0v, &tBi[r][cg]); unpack8(d1, &tBi[r][cg + 8]);
    }
    __syncthreads();

    const int c0 = tid >> 3;
    const int eg = tid & 7;
    float sR[2][8] = {}, sI[2][8] = {};
    for (int d0 = 0; d0 < 64; d0 += 8) {
        float q0r[8], q0i[8], q1r[8], q1i[8];
        *(float4*)&q0r[0] = *(const float4*)&tAr[c0][d0];
        *(float4*)&q0r[4] = *(const float4*)&tAr[c0][d0 + 4];
        *(float4*)&q0i[0] = *(const float4*)&tAi[c0][d0];
        *(float4*)&q0i[4] = *(const float4*)&tAi[c0][d0 + 4];
        *(float4*)&q1r[0] = *(const float4*)&tAr[c0 + 32][d0];
        *(float4*)&q1r[4] = *(const float4*)&tAr[c0 + 32][d0 + 4];
        *(float4*)&q1i[0] = *(const float4*)&tAi[c0 + 32][d0];
        *(float4*)&q1i[4] = *(const float4*)&tAi[c0 + 32][d0 + 4];
        #pragma unroll
        for (int ee = 0; ee < 8; ++ee) {
            const int e = eg + 8 * ee;
            float kvr[8], kvi[8];
            *(float4*)&kvr[0] = *(const float4*)&tBr[e][d0];
            *(float4*)&kvr[4] = *(const float4*)&tBr[e][d0 + 4];
            *(float4*)&kvi[0] = *(const float4*)&tBi[e][d0];
            *(float4*)&kvi[4] = *(const float4*)&tBi[e][d0 + 4];
            #pragma unroll
            for (int d = 0; d < 8; ++d) {
                sR[0][ee] = fmaf(q0r[d], kvr[d], sR[0][ee]);
                sR[0][ee] = fmaf(q0i[d], kvi[d], sR[0][ee]);
                sI[0][ee] = fmaf(q0r[d], kvi[d], sI[0][ee]);
                sI[0][ee] = fmaf(-q0i[d], kvr[d], sI[0][ee]);
                sR[1][ee] = fmaf(q1r[d], kvr[d], sR[1][ee]);
                sR[1][ee] = fmaf(q1i[d], kvi[d], sR[1][ee]);
                sI[1][ee] = fmaf(q1r[d], kvi[d], sI[1][ee]);
                sI[1][ee] = fmaf(-q1i[d], kvr[d], sI[1][ee]);
            }
        }
    }
    __syncthreads();

    {
        const int r = tid >> 2;
        const int cg = (tid & 3) << 4;
        const size_t off = base + (size_t)r * 64 + cg;
        uint4 v0 = ((const uint4*)(Vr + off))[0], v1 = ((const uint4*)(Vr + off))[1];
        uint4 w0 = ((const uint4*)(Vi + off))[0], w1 = ((const uint4*)(Vi + off))[1];
        unpack8(v0, &tBr[r][cg]); unpack8(v1, &tBr[r][cg + 8]);
        unpack8(w0, &tBi[r][cg]); unpack8(w1, &tBi[r][cg + 8]);
    }

    {
        const float scale = 0.125f;
        float amp[2][8], ex[2][8];
        int mk[8];
        #pragma unroll
        for (int ee = 0; ee < 8; ++ee) mk[ee] = mask[b * 64 + eg + 8 * ee];
        float mx[2] = {-INFINITY, -INFINITY};
        #pragma unroll
        for (int j = 0; j < 2; ++j)
            #pragma unroll
            for (int ee = 0; ee < 8; ++ee) {
                const float srv = sR[j][ee] * scale, siv = sI[j][ee] * scale;
                sR[j][ee] = srv; sI[j][ee] = siv;
                float a = sqrtf(fmaf(srv, srv, siv * siv));
                if (mk[ee] == 0) a = MIN_VALUE_F;
                amp[j][ee] = a;
                mx[j] = fmaxf(mx[j], a);
            }
        #pragma unroll
        for (int off = 1; off < 8; off <<= 1) {
            mx[0] = fmaxf(mx[0], __shfl_xor(mx[0], off, 64));
            mx[1] = fmaxf(mx[1], __shfl_xor(mx[1], off, 64));
        }
        float sm[2] = {0.f, 0.f};
        #pragma unroll
        for (int j = 0; j < 2; ++j)
            #pragma unroll
            for (int ee = 0; ee < 8; ++ee) {
                const float e_ = expf(amp[j][ee] - mx[j]);
                ex[j][ee] = e_; sm[j] += e_;
            }
        #pragma unroll
        for (int off = 1; off < 8; off <<= 1) {
            sm[0] += __shfl_xor(sm[0], off, 64);
            sm[1] += __shfl_xor(sm[1], off, 64);
        }
        #pragma unroll
        for (int j = 0; j < 2; ++j) {
            const int c = c0 + 32 * j;
            #pragma unroll
            for (int ee = 0; ee < 8; ++ee) {
                const int e = eg + 8 * ee;
                const float w = ex[j][ee] / (sm[j] * amp[j][ee]);
                tAr[c][e] = (mk[ee] == 0) ? 0.f : w * sR[j][ee];
                tAi[c][e] = (mk[ee] == 0) ? 0.f : w * sI[j][ee];
            }
        }
    }
    __syncthreads();

    const int dg = (tid & 7) << 3;
    float xR[2][8] = {}, xI[2][8] = {};
    for (int e0 = 0; e0 < 64; e0 += 8) {
        float a0r[8], a0i[8], a1r[8], a1i[8];
        *(float4*)&a0r[0] = *(const float4*)&tAr[c0][e0];
        *(float4*)&a0r[4] = *(const float4*)&tAr[c0][e0 + 4];
        *(float4*)&a0i[0] = *(const float4*)&tAi[c0][e0];
        *(float4*)&a0i[4] = *(const float4*)&tAi[c0][e0 + 4];
        *(float4*)&a1r[0] = *(const float4*)&tAr[c0 + 32][e0];
        *(float4*)&a1r[4] = *(const float4*)&tAr[c0 + 32][e0 + 4];
        *(float4*)&a1i[0] = *(const float4*)&tAi[c0 + 32][e0];
        *(float4*)&a1i[4] = *(const float4*)&tAi[c0 + 32][e0 + 4];
        #pragma unroll
        for (int ee = 0; ee < 8; ++ee) {
            const int e = e0 + ee;
            float vvr[8], vvi[8];
            *(float4*)&vvr[0] = *(const float4*)&tBr[e][dg];
            *(float4*)&vvr[4] = *(const float4*)&tBr[e][dg + 4];
            *(float4*)&vvi[0] = *(const float4*)&tBi[e][dg];
            *(float4*)&vvi[4] = *(const float4*)&tBi[e][dg + 4];
            #pragma unroll
            for (int d = 0; d < 8; ++d) {
                xR[0][d] = fmaf(a0r[ee], vvr[d], xR[0][d]);
                xR[0][d] = fmaf(-a0i[ee], vvi[d], xR[0][d]);
                xI[0][d] = fmaf(a0i[ee], vvr[d], xI[0][d]);
                xI[0][d] = fmaf(a0r[ee], vvi[d], xI[0][d]);
                xR[1][d] = fmaf(a1r[ee], vvr[d], xR[1][d]);
                xR[1][d] = fmaf(-a1i[ee], vvi[d], xR[1][d]);
                xI[1][d] = fmaf(a1i[ee], vvr[d], xI[1][d]);
                xI[1][d] = fmaf(a1r[ee], vvi[d], xI[1][d]);
            }
        }
    }
    #pragma unroll
    for (int j = 0; j < 2; ++j) {
        const int c = c0 + 32 * j;
        const size_t xo = (((size_t)(b * 64 + c) * 256) + t) * 256 + h * 64 + dg;
        uint4 ur, ui;
        ur.x = (unsigned)f2bf(xR[j][0]) | ((unsigned)f2bf(xR[j][1]) << 16);
        ur.y = (unsigned)f2bf(xR[j][2]) | ((unsigned)f2bf(xR[j][3]) << 16);
        ur.z = (unsigned)f2bf(xR[j][4]) | ((unsigned)f2bf(xR[j][5]) << 16);
        ur.w = (unsigned)f2bf(xR[j][6]) | ((unsigned)f2bf(xR[j][7]) << 16);
        ui.x = (unsigned)f2bf(xI[j][0]) | ((unsigned)f2bf(xI[j][1]) << 16);
        ui.y = (unsigned)f2bf(xI[j][2]) | ((unsigned)f2bf(xI[j][3]) << 16);
        ui.z = (unsigned)f2bf(xI[j][4]) | ((unsigned)f2bf(xI[j][5]) << 16);
        ui.w = (unsigned)f2bf(xI[j][6]) | ((unsigned)f2bf(xI[j][7]) << 16);
        *(uint4*)(Xr + xo) = ur;
        *(uint4*)(Xi + xo) = ui;
    }
}

// ---------------- Stage 3: complex output projection via MFMA ----------------
__global__ __launch_bounds__(256, 2)
void oproj_mfma(const unsigned short* __restrict__ Xr_g, const unsigned short* __restrict__ Xi_g,
                const unsigned short* __restrict__ wimg,   // wo_r, wo_i images
                const float* __restrict__ bo_r, const float* __restrict__ bo_i,
                float* __restrict__ outr, float* __restrict__ outi)
{
    __shared__ __align__(16) unsigned short As_r[8192], As_i[8192], Ws_r[8192], Ws_i[8192];
    const int tid = threadIdx.x;
    const int lane = tid & 63, wv = tid >> 6;
    const int wm = (wv >> 1) * 64, wn = (wv & 1) * 64;
    const int m0 = blockIdx.x * 128;
    const int nb = blockIdx.y;
    f32x4 accR[4][4] = {}, accI[4][4] = {};

    for (int s = 0; s < 4; ++s) {
        const unsigned short* wrp = wimg + (nb * 4 + s) * 8192;
        const unsigned short* wip = wimg + 65536 + (nb * 4 + s) * 8192;
        #pragma unroll
        for (int cc = 0; cc < 4; ++cc) {
            const int offs = wv * 2048 + cc * 512;
            glds16(wrp + offs + lane * 8, &Ws_r[offs]);
            glds16(wip + offs + lane * 8, &Ws_i[offs]);
            // A: X is bf16 row-major; inverse-swizzled per-lane source, linear LDS dest
            const int p = (offs + lane * 8) << 1;          // byte pos in image
            const int m = p >> 7;
            const int kl = ((p & 127) ^ ((m & 7) << 4)) >> 1;
            const size_t so = (size_t)(m0 + m) * 256 + s * 64 + kl;
            glds16(Xr_g + so, &As_r[offs]);
            glds16(Xi_g + so, &As_i[offs]);
        }
        __syncthreads();
        #pragma unroll
        for (int ks = 0; ks < 2; ++ks) {
            const int kb = ks * 32 + ((lane >> 4) << 3);
            bfrag ar[4], ai[4], nai[4];
            #pragma unroll
            for (int mf = 0; mf < 4; ++mf) {
                const int m = wm + mf * 16 + (lane & 15);
                const int idx = (m * 64 + kb) ^ ((m & 7) << 3);
                ar[mf] = *(const bfrag*)&As_r[idx];
                ai[mf] = *(const bfrag*)&As_i[idx];
                nai[mf] = negf(ai[mf]);
            }
            #pragma unroll
            for (int nf = 0; nf < 4; ++nf) {
                const int n = wn + nf * 16 + (lane & 15);
                const int idx = (n * 64 + kb) ^ ((n & 7) << 3);
                const bfrag brf = *(const bfrag*)&Ws_r[idx];
                const bfrag bif = *(const bfrag*)&Ws_i[idx];
                #pragma unroll
                for (int mf = 0; mf < 4; ++mf) {
                    accR[mf][nf] = __builtin_amdgcn_mfma_f32_16x16x32_bf16(ar[mf], brf, accR[mf][nf], 0, 0, 0);
                    accR[mf][nf] = __builtin_amdgcn_mfma_f32_16x16x32_bf16(nai[mf], bif, accR[mf][nf], 0, 0, 0);
                    accI[mf][nf] = __builtin_amdgcn_mfma_f32_16x16x32_bf16(ai[mf], brf, accI[mf][nf], 0, 0, 0);
                    accI[mf][nf] = __builtin_amdgcn_mfma_f32_16x16x32_bf16(ar[mf], bif, accI[mf][nf], 0, 0, 0);
                }
            }
        }
        __syncthreads();
    }
    const int colL = lane & 15, rowL = (lane >> 4) << 2;
    #pragma unroll
    for (int nf = 0; nf < 4; ++nf) {
        const int n = nb * 128 + wn + nf * 16 + colL;
        const float vbr = bo_r[n], vbi = bo_i[n];
        const float addR = vbr - vbi, addI = vbr + vbi;
        #pragma unroll
        for (int mf = 0; mf < 4; ++mf) {
            const int mb = m0 + wm + mf * 16 + rowL;
            #pragma unroll
            for (int r = 0; r < 4; ++r) {
                const size_t o = (size_t)(mb + r) * 256 + n;
                outr[o] = accR[mf][nf][r] + addR;
                outi[o] = accI[mf][nf][r] + addI;
            }
        }
    }
}

extern "C" void kernel_launch(void* const* d_in, const int* in_sizes, int n_in,
                              void* d_out, int out_size, void* d_ws, size_t ws_size,
                              hipStream_t stream)
{
    (void)in_sizes; (void)n_in; (void)out_size; (void)ws_size;
    const float* q_r = (const float*)d_in[0];
    const float* q_i = (const float*)d_in[1];
    const float* k_r = (const float*)d_in[2];
    const float* k_i = (const float*)d_in[3];
    const float* v_r = (const float*)d_in[4];
    const float* v_i = (const float*)d_in[5];
    const int* mask = (const int*)d_in[6];
    const float* wq_r = (const float*)d_in[7];
    const float* wq_i = (const float*)d_in[8];
    const float* bq_r = (const float*)d_in[9];
    const float* bq_i = (const float*)d_in[10];
    const float* wk_r = (const float*)d_in[11];
    const float* wk_i = (const float*)d_in[12];
    const float* bk_r = (const float*)d_in[13];
    const float* bk_i = (const float*)d_in[14];
    const float* wv_r = (const float*)d_in[15];
    const float* wv_i = (const float*)d_in[16];
    const float* bv_r = (const float*)d_in[17];
    const float* bv_i = (const float*)d_in[18];
    const float* wo_r = (const float*)d_in[19];
    const float* wo_i = (const float*)d_in[20];
    const float* bo_r = (const float*)d_in[21];
    const float* bo_i = (const float*)d_in[22];

    const size_t TS = 16777216;
    unsigned short* ws = (unsigned short*)d_ws;
    unsigned short* Q = ws;                      // Qr,Qi,Kr,Ki,Vr,Vi: 6 x TS
    unsigned short* Xr = ws + 6 * TS;
    unsigned short* Xi = ws + 7 * TS;
    unsigned short* wimg_qkv = ws + 6 * TS;      // overlaid on X region (dead until attn)
    unsigned short* wimg_o = ws;                 // overlaid on Q region (dead after attn)

    wprep_kernel<<<dim3(32, 6), 256, 0, stream>>>(wq_r, wq_i, wk_r, wk_i, wv_r, wv_i, wimg_qkv);
    proj_mfma<<<dim3(512, 2, 3), 256, 0, stream>>>(q_r, q_i, k_r, k_i, v_r, v_i, wimg_qkv,
                                                   bq_r, bq_i, bk_r, bk_i, bv_r, bv_i, ws);
    attn_kernel<<<dim3(4096), 256, 0, stream>>>(Q, Q + TS, Q + 2 * TS, Q + 3 * TS,
                                                Q + 4 * TS, Q + 5 * TS, mask, Xr, Xi);
    wprep_kernel<<<dim3(32, 2), 256, 0, stream>>>(wo_r, wo_i, wo_r, wo_r, wo_r, wo_r, wimg_o);
    oproj_mfma<<<dim3(512, 2), 256, 0, stream>>>(Xr, Xi, wimg_o, bo_r, bo_i,
                                                 (float*)d_out, (float*)d_out + TS);
}

// Round 3
// 342.471 us; speedup vs baseline: 5.4483x; 1.6399x over previous
//
#include <hip/hip_runtime.h>
#include <hip/hip_bf16.h>
#include <cstddef>

#define MIN_VALUE_F (-3.402823466e38f)

// B=4, C=64, T=256, D=256, H=4, DK=64, OUT=256, M = B*C*T = 65536

typedef __attribute__((ext_vector_type(8))) __bf16 bfrag;    // MFMA A/B operand (4 VGPR)
typedef __attribute__((ext_vector_type(4))) float f32x4;     // MFMA C/D operand

__device__ __forceinline__ float bf2f(unsigned int u) {
    union { unsigned int i; float f; } v; v.i = u << 16; return v.f;
}
__device__ __forceinline__ unsigned short f2bf(float f) {
    union { float f; unsigned int i; } v; v.f = f;
    return (unsigned short)((v.i + 0x7fffu + ((v.i >> 16) & 1u)) >> 16);
}
__device__ __forceinline__ unsigned int cvt2(float a, float b) {
    __hip_bfloat16 lo = __float2bfloat16(a);
    __hip_bfloat16 hi = __float2bfloat16(b);
    union { __hip_bfloat16 h[2]; unsigned int u; } x;
    x.h[0] = lo; x.h[1] = hi;
    return x.u;
}
__device__ __forceinline__ bfrag negf(bfrag v) {
    union { bfrag b; unsigned int u[4]; } x; x.b = v;
    #pragma unroll
    for (int i = 0; i < 4; ++i) x.u[i] ^= 0x80008000u;
    return x.b;
}

typedef __attribute__((address_space(3))) void lds_void_t;
typedef const __attribute__((address_space(1))) void gmem_void_t;
__device__ __forceinline__ void glds16(const void* g, void* l) {
    __builtin_amdgcn_global_load_lds((gmem_void_t*)g, (lds_void_t*)l, 16, 0, 0);
}

// fragment read from XOR-swizzled row-major 64x64 bf16 tile (row stride 64 ushorts)
__device__ __forceinline__ bfrag rdfrag(const unsigned short* arr, int row, int slot) {
    const int s = slot ^ (row & 7);
    return *(const bfrag*)&arr[row * 64 + s * 8];
}

// ---------------- Weight prepass: f32 (K=256,N=256) -> bf16 pre-swizzled LDS images ----
__global__ __launch_bounds__(256)
void wprep_kernel(const float* __restrict__ w0, const float* __restrict__ w1,
                  const float* __restrict__ w2, const float* __restrict__ w3,
                  const float* __restrict__ w4, const float* __restrict__ w5,
                  unsigned short* __restrict__ dst)
{
    const int my = blockIdx.y;
    const float* wsrc[6] = {w0, w1, w2, w3, w4, w5};
    const float* w = wsrc[my];
    const int cid = blockIdx.x * 256 + threadIdx.x;   // 0..8191 chunks (16B each)
    const int img = cid >> 10;                        // 0..7  (nb*4 + s)
    const int nb = img >> 2, s = img & 3;
    const int u0 = (cid & 1023) << 3;                 // ushort pos in image
    const int n_loc = u0 >> 6;
    const int k_src = (u0 & 63) ^ ((n_loc & 7) << 3);
    const int n = nb * 128 + n_loc;
    const int kbase = s * 64 + k_src;
    unsigned int p[4];
    #pragma unroll
    for (int jj = 0; jj < 4; ++jj) {
        const float a = w[(size_t)(kbase + 2 * jj) * 256 + n];
        const float b = w[(size_t)(kbase + 2 * jj + 1) * 256 + n];
        p[jj] = cvt2(a, b);
    }
    uint4 q; q.x = p[0]; q.y = p[1]; q.z = p[2]; q.w = p[3];
    *(uint4*)&dst[(size_t)my * 65536 + img * 8192 + u0] = q;
}

// ---------------- Stage 1: complex QKV projection via MFMA ----------------
__global__ __launch_bounds__(256, 2)
void proj_mfma(const float* __restrict__ xq_r, const float* __restrict__ xq_i,
               const float* __restrict__ xk_r, const float* __restrict__ xk_i,
               const float* __restrict__ xv_r, const float* __restrict__ xv_i,
               const unsigned short* __restrict__ wimg,
               const float* __restrict__ bq_r, const float* __restrict__ bq_i,
               const float* __restrict__ bk_r, const float* __restrict__ bk_i,
               const float* __restrict__ bv_r, const float* __restrict__ bv_i,
               unsigned short* __restrict__ ws_out)
{
    __shared__ __align__(16) unsigned short As_r[8192], As_i[8192], Ws_r[8192], Ws_i[8192];
    const int pz = blockIdx.z;
    const float *xr, *xi, *br_, *bi_;
    if (pz == 0)      { xr = xq_r; xi = xq_i; br_ = bq_r; bi_ = bq_i; }
    else if (pz == 1) { xr = xk_r; xi = xk_i; br_ = bk_r; bi_ = bk_i; }
    else              { xr = xv_r; xi = xv_i; br_ = bv_r; bi_ = bv_i; }
    const unsigned short* wr_img = wimg + (size_t)pz * 131072;
    const unsigned short* wi_img = wr_img + 65536;
    unsigned short* outr = ws_out + (size_t)pz * 2 * 16777216;
    unsigned short* outi = outr + 16777216;

    const int tid = threadIdx.x;
    const int lane = tid & 63, wv = tid >> 6;
    const int wm = (wv >> 1) * 64, wn = (wv & 1) * 64;
    const int m0 = blockIdx.x * 128;
    const int nb = blockIdx.y;
    const int sm = tid >> 3;
    const int sk = (tid & 7) << 3;
    f32x4 accR[4][4] = {}, accI[4][4] = {};

    for (int s = 0; s < 4; ++s) {
        const unsigned short* wrp = wr_img + (nb * 4 + s) * 8192;
        const unsigned short* wip = wi_img + (nb * 4 + s) * 8192;
        #pragma unroll
        for (int cc = 0; cc < 4; ++cc) {
            const int offs = wv * 2048 + cc * 512;
            glds16(wrp + offs + lane * 8, &Ws_r[offs]);
            glds16(wip + offs + lane * 8, &Ws_i[offs]);
        }
        #pragma unroll
        for (int it = 0; it < 4; ++it) {
            const int m = it * 32 + sm;
            const float* sr = xr + (size_t)(m0 + m) * 256 + s * 64 + sk;
            const float* si = xi + (size_t)(m0 + m) * 256 + s * 64 + sk;
            const float4 a0 = *(const float4*)sr;
            const float4 a1 = *(const float4*)(sr + 4);
            const float4 b0 = *(const float4*)si;
            const float4 b1 = *(const float4*)(si + 4);
            const int idx = (m * 64 + sk) ^ ((m & 7) << 3);
            uint4 pr, pi;
            pr.x = cvt2(a0.x, a0.y); pr.y = cvt2(a0.z, a0.w);
            pr.z = cvt2(a1.x, a1.y); pr.w = cvt2(a1.z, a1.w);
            pi.x = cvt2(b0.x, b0.y); pi.y = cvt2(b0.z, b0.w);
            pi.z = cvt2(b1.x, b1.y); pi.w = cvt2(b1.z, b1.w);
            *(uint4*)&As_r[idx] = pr;
            *(uint4*)&As_i[idx] = pi;
        }
        __syncthreads();
        #pragma unroll
        for (int ks = 0; ks < 2; ++ks) {
            const int kb = ks * 32 + ((lane >> 4) << 3);
            bfrag ar[4], ai[4], nai[4];
            #pragma unroll
            for (int mf = 0; mf < 4; ++mf) {
                const int m = wm + mf * 16 + (lane & 15);
                const int idx = (m * 64 + kb) ^ ((m & 7) << 3);
                ar[mf] = *(const bfrag*)&As_r[idx];
                ai[mf] = *(const bfrag*)&As_i[idx];
                nai[mf] = negf(ai[mf]);
            }
            #pragma unroll
            for (int nf = 0; nf < 4; ++nf) {
                const int n = wn + nf * 16 + (lane & 15);
                const int idx = (n * 64 + kb) ^ ((n & 7) << 3);
                const bfrag brf = *(const bfrag*)&Ws_r[idx];
                const bfrag bif = *(const bfrag*)&Ws_i[idx];
                #pragma unroll
                for (int mf = 0; mf < 4; ++mf) {
                    accR[mf][nf] = __builtin_amdgcn_mfma_f32_16x16x32_bf16(ar[mf], brf, accR[mf][nf], 0, 0, 0);
                    accR[mf][nf] = __builtin_amdgcn_mfma_f32_16x16x32_bf16(nai[mf], bif, accR[mf][nf], 0, 0, 0);
                    accI[mf][nf] = __builtin_amdgcn_mfma_f32_16x16x32_bf16(ai[mf], brf, accI[mf][nf], 0, 0, 0);
                    accI[mf][nf] = __builtin_amdgcn_mfma_f32_16x16x32_bf16(ar[mf], bif, accI[mf][nf], 0, 0, 0);
                }
            }
        }
        __syncthreads();
    }
    const int bc = m0 >> 8, b = bc >> 6, c = bc & 63, t0 = m0 & 255;
    const int colL = lane & 15, rowL = (lane >> 4) << 2;
    #pragma unroll
    for (int nf = 0; nf < 4; ++nf) {
        const int n_glob = nb * 128 + wn + nf * 16 + colL;
        const int h = n_glob >> 6, dk = n_glob & 63;
        const float vbr = br_[n_glob], vbi = bi_[n_glob];
        const float addR = vbr - vbi, addI = vbr + vbi;
        const size_t baseh = (((size_t)(b * 4 + h) * 256) * 64 + c) * 64 + dk;
        #pragma unroll
        for (int mf = 0; mf < 4; ++mf) {
            const int tb = t0 + wm + mf * 16 + rowL;
            #pragma unroll
            for (int r = 0; r < 4; ++r) {
                const size_t o = baseh + (size_t)(tb + r) * 4096;
                outr[o] = f2bf(accR[mf][nf][r] + addR);
                outi[o] = f2bf(accI[mf][nf][r] + addI);
            }
        }
    }
}

// ---------------- Stage 2: fused complex attention per (b,h,t), MFMA ----------------
// Per block: S^T[e][c] = mfma(K,Q); amplitude softmax over e (in-reg + 2 shfl);
// P(bf16) -> LDS (reuses Q space); X[c][d] = mfma(P, V^T).
__global__ __launch_bounds__(256)
void attn_mfma(const unsigned short* __restrict__ Qg_r, const unsigned short* __restrict__ Qg_i,
               const unsigned short* __restrict__ Kg_r, const unsigned short* __restrict__ Kg_i,
               const unsigned short* __restrict__ Vg_r, const unsigned short* __restrict__ Vg_i,
               const int* __restrict__ mask,
               unsigned short* __restrict__ Xr, unsigned short* __restrict__ Xi)
{
    __shared__ __align__(16) unsigned short sQr[4096], sQi[4096];   // Q, then P
    __shared__ __align__(16) unsigned short sKr[4096], sKi[4096];
    __shared__ __align__(16) unsigned short sVr[4608], sVi[4608];   // V^T, rows padded to 72
    __shared__ int smask[64];

    const int bht = blockIdx.x;
    const int b = bht >> 10;
    const int h = (bht >> 8) & 3;
    const int t = bht & 255;
    const size_t base = (size_t)bht * 4096;
    const int tid = threadIdx.x;
    const int lane = tid & 63, wv = tid >> 6;
    const int l15 = lane & 15, hi = lane >> 4;

    // ---- V rows -> registers (for transpose)
    const int ep = (lane & 31) * 2;            // even e
    const int dch = wv * 2 + (lane >> 5);      // d-chunk 0..7
    const unsigned short* vr0p = Vg_r + base + (size_t)ep * 64 + dch * 8;
    const unsigned short* vi0p = Vg_i + base + (size_t)ep * 64 + dch * 8;
    const uint4 vr0 = *(const uint4*)vr0p;
    const uint4 vr1 = *(const uint4*)(vr0p + 64);
    const uint4 vi0 = *(const uint4*)vi0p;
    const uint4 vi1 = *(const uint4*)(vi0p + 64);

    // ---- Q,K via global_load_lds, pre-swizzled source (linear LDS dest)
    #pragma unroll
    for (int i = 0; i < 2; ++i) {
        const int ch = wv * 128 + i * 64 + lane;
        const int r = ch >> 3, cg = ch & 7;
        const int so = r * 64 + ((cg ^ (r & 7)) << 3);
        const int dofs = (wv * 128 + i * 64) << 3;
        glds16(Qg_r + base + so, &sQr[dofs]);
        glds16(Qg_i + base + so, &sQi[dofs]);
        glds16(Kg_r + base + so, &sKr[dofs]);
        glds16(Kg_i + base + so, &sKi[dofs]);
    }
    if (tid < 64) smask[tid] = mask[b * 64 + tid];

    // ---- write V^T
    {
        union { uint4 v; unsigned short s[8]; } ar0, ar1, ai0, ai1;
        ar0.v = vr0; ar1.v = vr1; ai0.v = vi0; ai1.v = vi1;
        #pragma unroll
        for (int j = 0; j < 8; ++j) {
            const int d = dch * 8 + j;
            *(unsigned int*)&sVr[d * 72 + ep] = (unsigned)ar0.s[j] | ((unsigned)ar1.s[j] << 16);
            *(unsigned int*)&sVi[d * 72 + ep] = (unsigned)ai0.s[j] | ((unsigned)ai1.s[j] << 16);
        }
    }
    __syncthreads();

    // ---- scores: S^T[e][c], wave wv owns c-range wv*16..+15, all e
    const int cq = wv * 16 + l15;
    f32x4 aR[4] = {}, aI[4] = {};
    #pragma unroll
    for (int ks = 0; ks < 2; ++ks) {
        const int slot = ks * 4 + hi;
        const bfrag qr = rdfrag(sQr, cq, slot);
        const bfrag qi = rdfrag(sQi, cq, slot);
        const bfrag nqi = negf(qi);
        #pragma unroll
        for (int et = 0; et < 4; ++et) {
            const int re = et * 16 + l15;
            const bfrag kr = rdfrag(sKr, re, slot);
            const bfrag ki = rdfrag(sKi, re, slot);
            aR[et] = __builtin_amdgcn_mfma_f32_16x16x32_bf16(kr, qr, aR[et], 0, 0, 0);
            aR[et] = __builtin_amdgcn_mfma_f32_16x16x32_bf16(ki, qi, aR[et], 0, 0, 0);
            aI[et] = __builtin_amdgcn_mfma_f32_16x16x32_bf16(ki, qr, aI[et], 0, 0, 0);
            aI[et] = __builtin_amdgcn_mfma_f32_16x16x32_bf16(kr, nqi, aI[et], 0, 0, 0);
        }
    }
    __syncthreads();   // all waves done reading Q (sQr/sQi become P space)

    // ---- amplitude softmax over e (16 in-reg values + shfl_xor 16,32)
    const float scale = 0.125f;
    float amp[4][4], ex[4][4];
    float mx = MIN_VALUE_F;
    #pragma unroll
    for (int et = 0; et < 4; ++et) {
        #pragma unroll
        for (int r = 0; r < 4; ++r) {
            const float sr = aR[et][r] * scale;
            const float si = aI[et][r] * scale;
            float a = sqrtf(fmaf(sr, sr, si * si));
            if (smask[et * 16 + hi * 4 + r] == 0) a = MIN_VALUE_F;
            amp[et][r] = a;
            mx = fmaxf(mx, a);
        }
    }
    mx = fmaxf(mx, __shfl_xor(mx, 16, 64));
    mx = fmaxf(mx, __shfl_xor(mx, 32, 64));
    float sm = 0.f;
    #pragma unroll
    for (int et = 0; et < 4; ++et) {
        #pragma unroll
        for (int r = 0; r < 4; ++r) {
            const float e_ = expf(amp[et][r] - mx);
            ex[et][r] = e_; sm += e_;
        }
    }
    sm += __shfl_xor(sm, 16, 64);
    sm += __shfl_xor(sm, 32, 64);

    // ---- P = (ex/(sm*amp)) * s, bf16, into sQr/sQi (XOR-swizzled row cq)
    #pragma unroll
    for (int et = 0; et < 4; ++et) {
        float pr[4], pi[4];
        #pragma unroll
        for (int r = 0; r < 4; ++r) {
            const float w = ex[et][r] * __builtin_amdgcn_rcpf(sm * amp[et][r]);
            pr[r] = w * (aR[et][r] * scale);
            pi[r] = w * (aI[et][r] * scale);
        }
        const int pidx = cq * 64 + ((et * 16 + hi * 4) ^ ((cq & 7) << 3));
        uint2 ur, ui;
        ur.x = cvt2(pr[0], pr[1]); ur.y = cvt2(pr[2], pr[3]);
        ui.x = cvt2(pi[0], pi[1]); ui.y = cvt2(pi[2], pi[3]);
        *(uint2*)&sQr[pidx] = ur;
        *(uint2*)&sQi[pidx] = ui;
    }
    __syncthreads();

    // ---- X[c][d] = P V (complex); wave wv owns c-rows wv*16..+15
    f32x4 xR4[4] = {}, xI4[4] = {};
    #pragma unroll
    for (int ks = 0; ks < 2; ++ks) {
        const int slot = ks * 4 + hi;
        const bfrag pr = rdfrag(sQr, cq, slot);
        const bfrag pi = rdfrag(sQi, cq, slot);
        const bfrag npi = negf(pi);
        #pragma unroll
        for (int dt = 0; dt < 4; ++dt) {
            const int rd = dt * 16 + l15;
            const bfrag vr = *(const bfrag*)&sVr[rd * 72 + ks * 32 + hi * 8];
            const bfrag vi = *(const bfrag*)&sVi[rd * 72 + ks * 32 + hi * 8];
            xR4[dt] = __builtin_amdgcn_mfma_f32_16x16x32_bf16(pr, vr, xR4[dt], 0, 0, 0);
            xR4[dt] = __builtin_amdgcn_mfma_f32_16x16x32_bf16(npi, vi, xR4[dt], 0, 0, 0);
            xI4[dt] = __builtin_amdgcn_mfma_f32_16x16x32_bf16(pi, vr, xI4[dt], 0, 0, 0);
            xI4[dt] = __builtin_amdgcn_mfma_f32_16x16x32_bf16(pr, vi, xI4[dt], 0, 0, 0);
        }
    }

    // ---- store X to (B,C,T,D), feature = h*64 + d
    #pragma unroll
    for (int dt = 0; dt < 4; ++dt) {
        #pragma unroll
        for (int r = 0; r < 4; ++r) {
            const int c = wv * 16 + hi * 4 + r;
            const size_t o = (((size_t)(b * 64 + c) * 256) + t) * 256 + h * 64 + dt * 16 + l15;
            Xr[o] = f2bf(xR4[dt][r]);
            Xi[o] = f2bf(xI4[dt][r]);
        }
    }
}

// ---------------- Stage 3: complex output projection via MFMA ----------------
__global__ __launch_bounds__(256, 2)
void oproj_mfma(const unsigned short* __restrict__ Xr_g, const unsigned short* __restrict__ Xi_g,
                const unsigned short* __restrict__ wimg,
                const float* __restrict__ bo_r, const float* __restrict__ bo_i,
                float* __restrict__ outr, float* __restrict__ outi)
{
    __shared__ __align__(16) unsigned short As_r[8192], As_i[8192], Ws_r[8192], Ws_i[8192];
    const int tid = threadIdx.x;
    const int lane = tid & 63, wv = tid >> 6;
    const int wm = (wv >> 1) * 64, wn = (wv & 1) * 64;
    const int m0 = blockIdx.x * 128;
    const int nb = blockIdx.y;
    f32x4 accR[4][4] = {}, accI[4][4] = {};

    for (int s = 0; s < 4; ++s) {
        const unsigned short* wrp = wimg + (nb * 4 + s) * 8192;
        const unsigned short* wip = wimg + 65536 + (nb * 4 + s) * 8192;
        #pragma unroll
        for (int cc = 0; cc < 4; ++cc) {
            const int offs = wv * 2048 + cc * 512;
            glds16(wrp + offs + lane * 8, &Ws_r[offs]);
            glds16(wip + offs + lane * 8, &Ws_i[offs]);
            const int p = (offs + lane * 8) << 1;
            const int m = p >> 7;
            const int kl = ((p & 127) ^ ((m & 7) << 4)) >> 1;
            const size_t so = (size_t)(m0 + m) * 256 + s * 64 + kl;
            glds16(Xr_g + so, &As_r[offs]);
            glds16(Xi_g + so, &As_i[offs]);
        }
        __syncthreads();
        #pragma unroll
        for (int ks = 0; ks < 2; ++ks) {
            const int kb = ks * 32 + ((lane >> 4) << 3);
            bfrag ar[4], ai[4], nai[4];
            #pragma unroll
            for (int mf = 0; mf < 4; ++mf) {
                const int m = wm + mf * 16 + (lane & 15);
                const int idx = (m * 64 + kb) ^ ((m & 7) << 3);
                ar[mf] = *(const bfrag*)&As_r[idx];
                ai[mf] = *(const bfrag*)&As_i[idx];
                nai[mf] = negf(ai[mf]);
            }
            #pragma unroll
            for (int nf = 0; nf < 4; ++nf) {
                const int n = wn + nf * 16 + (lane & 15);
                const int idx = (n * 64 + kb) ^ ((n & 7) << 3);
                const bfrag brf = *(const bfrag*)&Ws_r[idx];
                const bfrag bif = *(const bfrag*)&Ws_i[idx];
                #pragma unroll
                for (int mf = 0; mf < 4; ++mf) {
                    accR[mf][nf] = __builtin_amdgcn_mfma_f32_16x16x32_bf16(ar[mf], brf, accR[mf][nf], 0, 0, 0);
                    accR[mf][nf] = __builtin_amdgcn_mfma_f32_16x16x32_bf16(nai[mf], bif, accR[mf][nf], 0, 0, 0);
                    accI[mf][nf] = __builtin_amdgcn_mfma_f32_16x16x32_bf16(ai[mf], brf, accI[mf][nf], 0, 0, 0);
                    accI[mf][nf] = __builtin_amdgcn_mfma_f32_16x16x32_bf16(ar[mf], bif, accI[mf][nf], 0, 0, 0);
                }
            }
        }
        __syncthreads();
    }
    const int colL = lane & 15, rowL = (lane >> 4) << 2;
    #pragma unroll
    for (int nf = 0; nf < 4; ++nf) {
        const int n = nb * 128 + wn + nf * 16 + colL;
        const float vbr = bo_r[n], vbi = bo_i[n];
        const float addR = vbr - vbi, addI = vbr + vbi;
        #pragma unroll
        for (int mf = 0; mf < 4; ++mf) {
            const int mb = m0 + wm + mf * 16 + rowL;
            #pragma unroll
            for (int r = 0; r < 4; ++r) {
                const size_t o = (size_t)(mb + r) * 256 + n;
                outr[o] = accR[mf][nf][r] + addR;
                outi[o] = accI[mf][nf][r] + addI;
            }
        }
    }
}

extern "C" void kernel_launch(void* const* d_in, const int* in_sizes, int n_in,
                              void* d_out, int out_size, void* d_ws, size_t ws_size,
                              hipStream_t stream)
{
    (void)in_sizes; (void)n_in; (void)out_size; (void)ws_size;
    const float* q_r = (const float*)d_in[0];
    const float* q_i = (const float*)d_in[1];
    const float* k_r = (const float*)d_in[2];
    const float* k_i = (const float*)d_in[3];
    const float* v_r = (const float*)d_in[4];
    const float* v_i = (const float*)d_in[5];
    const int* mask = (const int*)d_in[6];
    const float* wq_r = (const float*)d_in[7];
    const float* wq_i = (const float*)d_in[8];
    const float* bq_r = (const float*)d_in[9];
    const float* bq_i = (const float*)d_in[10];
    const float* wk_r = (const float*)d_in[11];
    const float* wk_i = (const float*)d_in[12];
    const float* bk_r = (const float*)d_in[13];
    const float* bk_i = (const float*)d_in[14];
    const float* wv_r = (const float*)d_in[15];
    const float* wv_i = (const float*)d_in[16];
    const float* bv_r = (const float*)d_in[17];
    const float* bv_i = (const float*)d_in[18];
    const float* wo_r = (const float*)d_in[19];
    const float* wo_i = (const float*)d_in[20];
    const float* bo_r = (const float*)d_in[21];
    const float* bo_i = (const float*)d_in[22];

    const size_t TS = 16777216;
    unsigned short* ws = (unsigned short*)d_ws;
    unsigned short* Q = ws;                      // Qr,Qi,Kr,Ki,Vr,Vi: 6 x TS
    unsigned short* Xr = ws + 6 * TS;
    unsigned short* Xi = ws + 7 * TS;
    unsigned short* wimg_qkv = ws + 6 * TS;      // overlaid on X region (dead until attn)
    unsigned short* wimg_o = ws;                 // overlaid on Q region (dead after attn)

    wprep_kernel<<<dim3(32, 6), 256, 0, stream>>>(wq_r, wq_i, wk_r, wk_i, wv_r, wv_i, wimg_qkv);
    proj_mfma<<<dim3(512, 2, 3), 256, 0, stream>>>(q_r, q_i, k_r, k_i, v_r, v_i, wimg_qkv,
                                                   bq_r, bq_i, bk_r, bk_i, bv_r, bv_i, ws);
    attn_mfma<<<dim3(4096), 256, 0, stream>>>(Q, Q + TS, Q + 2 * TS, Q + 3 * TS,
                                              Q + 4 * TS, Q + 5 * TS, mask, Xr, Xi);
    wprep_kernel<<<dim3(32, 2), 256, 0, stream>>>(wo_r, wo_i, wo_r, wo_r, wo_r, wo_r, wimg_o);
    oproj_mfma<<<dim3(512, 2), 256, 0, stream>>>(Xr, Xi, wimg_o, bo_r, bo_i,
                                                 (float*)d_out, (float*)d_out + TS);
}